// Round 5
// baseline (556.799 us; speedup 1.0000x reference)
//
#include <hip/hip_runtime.h>
#include <hip/hip_bf16.h>

typedef __bf16 bf16;
typedef __bf16 bf16x8 __attribute__((ext_vector_type(8)));
typedef float  f32x4  __attribute__((ext_vector_type(4)));

static constexpr int NB  = 16;
static constexpr int NN  = 2048;
static constexpr int HID = 128;

// async 16B global -> LDS. LDS dest is wave-uniform base (+ lane*16 in HW);
// global src address IS per-lane (must carry the lane term!).
__device__ __forceinline__ void gload_lds16(const bf16* g, bf16* l) {
    __builtin_amdgcn_global_load_lds(
        (const __attribute__((address_space(1))) unsigned int*)g,
        (__attribute__((address_space(3))) unsigned int*)l, 16, 0, 0);
}

#define WAITV(n) asm volatile("s_waitcnt vmcnt(" #n ")" ::: "memory")

// device-scope grid barrier; all blocks co-resident (1 block/CU by LDS).
__device__ __forceinline__ void gbar(unsigned* cnt, unsigned nb) {
    __syncthreads();
    if (threadIdx.x == 0) {
        __threadfence();   // agent release: my global writes visible
        __hip_atomic_fetch_add(cnt, 1u, __ATOMIC_ACQ_REL, __HIP_MEMORY_SCOPE_AGENT);
        while (__hip_atomic_load(cnt, __ATOMIC_ACQUIRE, __HIP_MEMORY_SCOPE_AGENT) < nb)
            __builtin_amdgcn_s_sleep(2);
        __threadfence();   // agent acquire: invalidate L1/L2 before reading others' data
    }
    __syncthreads();
}

// ---------------------------------------------------------------------------
// Tiled layouts ("LDS images", 16 KB tiles of 1024 16B-chunks):
//   A-tile (128 rows x 64 k): chunk p = row*8 + (kc ^ (row&7)), kc = k/8
//   B-tile (128 n   x 64 k): same formula with n as row
//   adjT[b][mtile(16)][kk(32)] tiles ; xTt/hT: [b][kk(32)] tiles
//   WTg per layer: 2048 chunks: chunk = n*16 + half*8 + (kc8 ^ (n&7)),
//     half = k>>6, kc8 = (k&63)>>3  (k-contig bf16x8 fragments of W^T[n][k])
// ---------------------------------------------------------------------------

// prep: W (128x128 fp32, [k][n]) -> swizzled WT tiles; also zero sync counters
__global__ __launch_bounds__(256) void prep_wt(const float* __restrict__ W0,
                                               const float* __restrict__ W1,
                                               const float* __restrict__ W2,
                                               bf16* __restrict__ WTg,
                                               unsigned* __restrict__ sync) {
    int l = blockIdx.x;
    int tid = threadIdx.x;
    if (l == 0 && tid < 64) sync[tid] = 0u;
    const float* W = (l == 0) ? W0 : (l == 1) ? W1 : W2;
    bf16* out = WTg + l * 16384;
#pragma unroll
    for (int i = 0; i < 8; ++i) {
        int p = i * 256 + tid;                 // [0,2048)
        int n = p >> 4, half = (p >> 3) & 1, cs = p & 7;
        int kc = cs ^ (n & 7);
        int kbase = half * 64 + kc * 8;
        bf16x8 o;
#pragma unroll
        for (int r = 0; r < 8; ++r) o[r] = (bf16)W[(kbase + r) * 128 + n];
        *(bf16x8*)(out + p * 8) = o;
    }
}

// prep: x (16,2048,128) fp32 -> xTt tiled bf16 B-tiles
__global__ __launch_bounds__(256) void prep_xt(const float* __restrict__ x,
                                               bf16* __restrict__ xTt) {
    __shared__ bf16 T[128 * 136];
    const int blk = blockIdx.x;            // 256 blocks: 16 node-tiles x 16 b
    const int b = blk >> 4, node0 = (blk & 15) * 128;
    const int tid = threadIdx.x;
    const float* xb = x + ((size_t)b * NN + node0) * HID;
#pragma unroll
    for (int i = 0; i < 64; ++i) {
        int idx = i * 256 + tid;
        int node = idx >> 7, hid = idx & 127;
        T[hid * 136 + node] = (bf16)xb[(size_t)node * HID + hid];
    }
    __syncthreads();
#pragma unroll
    for (int i = 0; i < 8; ++i) {
        int p = i * 256 + tid;                 // [0,2048) chunks (2 tiles)
        int half = p >> 10, p1 = p & 1023;
        int n = p1 >> 3, cs = p1 & 7, c = cs ^ (n & 7), m = half * 64 + c * 8;
        *(bf16x8*)(xTt + ((size_t)b * 32 + (node0 >> 6) + half) * 8192 + p1 * 8)
            = *(const bf16x8*)(T + n * 136 + m);
    }
}

// ---------------------------------------------------------------------------
// one layer: g = adj[b](128-row slab) @ h[b]; then h' = relu(LN(g@W + bias)).
// R3-verbatim body (best measured). BM=128, BK=64, 32 K-steps, 8 waves.
// AMODE 1: A from fp32 adj (coalesced 1KB/wave segs) + tiled side-write adjT.
// AMODE 2: A from adjT via linear gload_lds; counted vmcnt(4) 2-deep pipe.
// ---------------------------------------------------------------------------
template<int AMODE, bool FINAL>
__device__ __forceinline__ void layer_run(
        bf16* lds,
        const float* __restrict__ Afb,   // adj batch base (fp32), AMODE1 only
        bf16* __restrict__ Atl,          // adjT tile base for (b, mtile)
        const bf16* __restrict__ Btb,    // B-tile base for batch b
        const bf16* __restrict__ WTg,    // this layer's swizzled W
        const float* __restrict__ bias, const float* __restrict__ gam,
        const float* __restrict__ bet,
        bf16* __restrict__ hOut, float* __restrict__ outF,
        int b, int mtile, int m0) {
    bf16* WTl = lds + 32768;

    const int tid = threadIdx.x, wave = tid >> 6, lane = tid & 63;
    const int c0 = lane & 15, q = lane >> 4;
    const int wm = wave >> 1, wn = wave & 1;

    f32x4 acc[2][4] = {};

    // stage WT (2048 chunks, linear): 4 loads/wave
#pragma unroll
    for (int j = 0; j < 4; ++j) {
        int cb = j * 512 + wave * 64;
        gload_lds16(WTg + (size_t)(cb + lane) * 8, WTl + cb * 8);
    }

    auto stageA2 = [&](int buf, int kk) {    // 2 loads/wave, linear 16KB
#pragma unroll
        for (int j = 0; j < 2; ++j) {
            int cb = j * 512 + wave * 64;
            gload_lds16(Atl + (size_t)kk * 8192 + (size_t)(cb + lane) * 8,
                        lds + buf * 16384 + cb * 8);
        }
    };
    auto stageB2 = [&](int buf, int kk) {    // 2 loads/wave, linear 16KB
#pragma unroll
        for (int j = 0; j < 2; ++j) {
            int cb = j * 512 + wave * 64;
            gload_lds16(Btb + (size_t)kk * 8192 + (size_t)(cb + lane) * 8,
                        lds + buf * 16384 + 8192 + cb * 8);
        }
    };
    auto compute = [&](int buf) {
        const bf16* As = lds + buf * 16384;
        const bf16* Bs = As + 8192;
#pragma unroll
        for (int ks = 0; ks < 2; ++ks) {
            bf16x8 af[2], bf_[4];
#pragma unroll
            for (int mt = 0; mt < 2; ++mt) {
                int row = wm * 32 + mt * 16 + c0;
                int cb = (ks * 4 + q) ^ (row & 7);
                af[mt] = *(const bf16x8*)(As + row * 64 + cb * 8);
            }
#pragma unroll
            for (int nt = 0; nt < 4; ++nt) {
                int row = wn * 64 + nt * 16 + c0;
                int cb = (ks * 4 + q) ^ (row & 7);
                bf_[nt] = *(const bf16x8*)(Bs + row * 64 + cb * 8);
            }
#pragma unroll
            for (int mt = 0; mt < 2; ++mt)
#pragma unroll
                for (int nt = 0; nt < 4; ++nt)
                    acc[mt][nt] = __builtin_amdgcn_mfma_f32_16x16x32_bf16(
                        af[mt], bf_[nt], acc[mt][nt], 0, 0, 0);
        }
    };

    if constexpr (AMODE == 1) {
        int grow[2], gcb[2];
#pragma unroll
        for (int j = 0; j < 2; ++j) {
            int gi = j * 512 + tid;
            grow[j] = gi >> 3; gcb[j] = gi & 7;
        }
        f32x4 va[2], vb[2];
        auto loadA = [&](int kk) {
#pragma unroll
            for (int j = 0; j < 2; ++j) {
                const float* s = Afb + (size_t)(m0 + grow[j]) * NN + kk * 64 + gcb[j] * 8;
                va[j] = *(const f32x4*)s;
                vb[j] = *(const f32x4*)(s + 4);
            }
        };
        auto writeA = [&](int buf, int kk) {
#pragma unroll
            for (int j = 0; j < 2; ++j) {
                bf16x8 o = {(bf16)va[j].x, (bf16)va[j].y, (bf16)va[j].z, (bf16)va[j].w,
                            (bf16)vb[j].x, (bf16)vb[j].y, (bf16)vb[j].z, (bf16)vb[j].w};
                int ch = grow[j] * 8 + (gcb[j] ^ (grow[j] & 7));
                *(bf16x8*)(lds + buf * 16384 + ch * 8) = o;
                *(bf16x8*)(Atl + (size_t)kk * 8192 + ch * 8) = o;  // tiled side-write
            }
        };
        loadA(0); stageB2(0, 0); writeA(0, 0);
        __syncthreads();
        int cur = 0;
        for (int kk = 0; kk < 32; ++kk) {
            if (kk < 31) { loadA(kk + 1); stageB2(cur ^ 1, kk + 1); }
            compute(cur);
            if (kk < 31) writeA(cur ^ 1, kk + 1);
            __syncthreads();
            cur ^= 1;
        }
    } else {
        // prologue: WT(4) + tile0(4) + tile1(4) outstanding per wave
        stageA2(0, 0); stageB2(0, 0);
        stageA2(1, 1); stageB2(1, 1);
#pragma unroll 1
        for (int kk = 0; kk < 32; ++kk) {
            // in-order VMEM retirement: <=4 outstanding => tile kk landed
            if (kk < 31) WAITV(4);
            else         WAITV(0);
            __builtin_amdgcn_s_barrier();
            asm volatile("" ::: "memory");
            compute(kk & 1);
            asm volatile("" ::: "memory");
            __builtin_amdgcn_s_barrier();   // all waves done reading buf kk&1
            if (kk < 30) { stageA2(kk & 1, kk + 2); stageB2(kk & 1, kk + 2); }
        }
        __syncthreads();
    }

    // ---- epilogue: store g-tile bf16 to LDS [128][136] (dbuf area dead) ----
    bf16* G = lds;
#pragma unroll
    for (int mt = 0; mt < 2; ++mt)
#pragma unroll
        for (int r = 0; r < 4; ++r) {
            int row = wm * 32 + mt * 16 + q * 4 + r;
#pragma unroll
            for (int nt = 0; nt < 4; ++nt) {
                int col = wn * 64 + nt * 16 + c0;
                G[row * 136 + col] = (bf16)acc[mt][nt][r];
            }
        }
    __syncthreads();

    // ---- W-GEMM: h(128x128) = G @ W ; wave w owns rows [w*16, w*16+16) ----
    f32x4 a2[8] = {};
    {
        const int gr = wave * 16 + c0;
#pragma unroll
        for (int ks = 0; ks < 4; ++ks) {
            bf16x8 af = *(const bf16x8*)(G + gr * 136 + ks * 32 + q * 8);
#pragma unroll
            for (int nt = 0; nt < 8; ++nt) {
                int n = nt * 16 + c0;
                int ch = n * 16 + (ks >> 1) * 8 + ((((ks & 1) << 2) | q) ^ (n & 7));
                bf16x8 bw = *(const bf16x8*)(WTl + ch * 8);
                a2[nt] = __builtin_amdgcn_mfma_f32_16x16x32_bf16(af, bw, a2[nt], 0, 0, 0);
            }
        }
    }

    // ---- bias + LN(over n=128) + ReLU ----
    float bv[8], gv[8], ev[8];
#pragma unroll
    for (int nt = 0; nt < 8; ++nt) {
        int n = nt * 16 + c0;
        bv[nt] = bias[n]; gv[nt] = gam[n]; ev[nt] = bet[n];
    }
    bf16* Cs = lds;  // reuse G area for transpose staging (post-barrier)
    if constexpr (!FINAL) __syncthreads();   // all W-GEMM reads of G done
#pragma unroll
    for (int r = 0; r < 4; ++r) {
        float v[8], s1 = 0.f, s2 = 0.f;
#pragma unroll
        for (int nt = 0; nt < 8; ++nt) {
            float xv = a2[nt][r] + bv[nt];
            v[nt] = xv; s1 += xv; s2 += xv * xv;
        }
#pragma unroll
        for (int off = 1; off < 16; off <<= 1) {
            s1 += __shfl_xor(s1, off);
            s2 += __shfl_xor(s2, off);
        }
        float mu = s1 * (1.f / 128.f);
        float var = s2 * (1.f / 128.f) - mu * mu;
        float rs = rsqrtf(var + 1e-5f);
        int row = wave * 16 + q * 4 + r;      // local row in [0,128)
        if constexpr (FINAL) {
            size_t ro = ((size_t)b * NN + m0 + row) * HID;
#pragma unroll
            for (int nt = 0; nt < 8; ++nt) {
                float o = fmaxf((v[nt] - mu) * rs * gv[nt] + ev[nt], 0.f);
                outF[ro + nt * 16 + c0] = o;
            }
        } else {
#pragma unroll
            for (int nt = 0; nt < 8; ++nt) {
                float o = fmaxf((v[nt] - mu) * rs * gv[nt] + ev[nt], 0.f);
                Cs[(nt * 16 + c0) * 136 + row] = (bf16)o;
            }
        }
    }
    if constexpr (!FINAL) {
        __syncthreads();
        // write 2 tiled B-tiles (kk = mtile*2, mtile*2+1), fully linear
#pragma unroll
        for (int i = 0; i < 4; ++i) {
            int p = i * 512 + tid;            // [0,2048)
            int half = p >> 10, p1 = p & 1023;
            int n = p1 >> 3, cs = p1 & 7, c = cs ^ (n & 7), m = half * 64 + c * 8;
            *(bf16x8*)(hOut + ((size_t)b * 32 + mtile * 2 + half) * 8192 + p1 * 8)
                = *(const bf16x8*)(Cs + n * 136 + m);
        }
    }
}

// ---------------------------------------------------------------------------
// mega: all 3 layers, grid-barrier between. 256 blocks x 512 thr x 96KB LDS
// -> exactly 1 block/CU, all co-resident => manual grid sync is safe.
// ---------------------------------------------------------------------------
__global__ __launch_bounds__(512, 2) void mega(
        const float* __restrict__ adj, bf16* __restrict__ adjT,
        const bf16* __restrict__ xTt, const bf16* __restrict__ WTg,
        const float* __restrict__ b0, const float* __restrict__ g0, const float* __restrict__ e0,
        const float* __restrict__ b1, const float* __restrict__ g1, const float* __restrict__ e1,
        const float* __restrict__ b2, const float* __restrict__ g2, const float* __restrict__ e2,
        bf16* __restrict__ hT0, bf16* __restrict__ hT1,
        float* __restrict__ outF, unsigned* __restrict__ sync) {
    __shared__ __align__(16) bf16 lds[49152];   // 96 KB

    const int blk = blockIdx.x, xcd = blk & 7, jj = blk >> 3;
    const int b = xcd * 2 + (jj & 1);       // each XCD owns 2 batches
    const int mtile = jj >> 1, m0 = mtile * 128;

    const float* Afb = adj + (size_t)b * NN * NN;
    bf16* Atl = adjT + ((size_t)b * 16 + mtile) * (size_t)32 * 8192;

    layer_run<1, false>(lds, Afb, Atl, xTt + (size_t)b * 32 * 8192, WTg,
                        b0, g0, e0, hT0, nullptr, b, mtile, m0);
    gbar(sync + 0, 256);
    layer_run<2, false>(lds, Afb, Atl, hT0 + (size_t)b * 32 * 8192, WTg + 16384,
                        b1, g1, e1, hT1, nullptr, b, mtile, m0);
    gbar(sync + 1, 256);
    layer_run<2, true >(lds, Afb, Atl, hT1 + (size_t)b * 32 * 8192, WTg + 2 * 16384,
                        b2, g2, e2, nullptr, outF, b, mtile, m0);
}

// ---------------------------------------------------------------------------
extern "C" void kernel_launch(void* const* d_in, const int* in_sizes, int n_in,
                              void* d_out, int out_size, void* d_ws, size_t ws_size,
                              hipStream_t stream) {
    const float* x   = (const float*)d_in[0];
    const float* adj = (const float*)d_in[1];
    const float* W[3]  = {(const float*)d_in[2],  (const float*)d_in[6],  (const float*)d_in[10]};
    const float* bb[3] = {(const float*)d_in[3],  (const float*)d_in[7],  (const float*)d_in[11]};
    const float* gg[3] = {(const float*)d_in[4],  (const float*)d_in[8],  (const float*)d_in[12]};
    const float* be[3] = {(const float*)d_in[5],  (const float*)d_in[9],  (const float*)d_in[13]};

    char* ws = (char*)d_ws;
    size_t off = 0;
    auto alloc = [&](size_t bytes) {
        char* p = ws + off; off = (off + bytes + 255) & ~(size_t)255; return p;
    };
    unsigned* sync = (unsigned*)alloc(256);
    bf16* WTg  = (bf16*)alloc((size_t)3 * 16384 * 2);
    bf16* xTt  = (bf16*)alloc((size_t)NB * 32 * 8192 * 2);        // 8 MiB
    bf16* hT0  = (bf16*)alloc((size_t)NB * 32 * 8192 * 2);        // 8 MiB
    bf16* hT1  = (bf16*)alloc((size_t)NB * 32 * 8192 * 2);        // 8 MiB
    bf16* adjT = (bf16*)alloc((size_t)NB * 16 * 32 * 8192 * 2);   // 128 MiB

    float* outF = (float*)d_out;

    prep_wt<<<3, 256, 0, stream>>>(W[0], W[1], W[2], WTg, sync);
    prep_xt<<<256, 256, 0, stream>>>(x, xTt);

    mega<<<256, 512, 0, stream>>>(adj, adjT, xTt, WTg,
                                  bb[0], gg[0], be[0],
                                  bb[1], gg[1], be[1],
                                  bb[2], gg[2], be[2],
                                  hT0, hT1, outF, sync);
}

// Round 6
// 513.872 us; speedup vs baseline: 1.0835x; 1.0835x over previous
//
#include <hip/hip_runtime.h>
#include <hip/hip_bf16.h>

typedef __bf16 bf16;
typedef __bf16 bf16x8 __attribute__((ext_vector_type(8)));
typedef float  f32x4  __attribute__((ext_vector_type(4)));

static constexpr int NB  = 16;
static constexpr int NN  = 2048;
static constexpr int HID = 128;

// async 16B global -> LDS. LDS dest is wave-uniform base (+ lane*16 in HW);
// global src address IS per-lane (must carry the lane term!).
__device__ __forceinline__ void gload_lds16(const bf16* g, bf16* l) {
    __builtin_amdgcn_global_load_lds(
        (const __attribute__((address_space(1))) unsigned int*)g,
        (__attribute__((address_space(3))) unsigned int*)l, 16, 0, 0);
}

#define WAITV(n) asm volatile("s_waitcnt vmcnt(" #n ")" ::: "memory")

// ---------------------------------------------------------------------------
// Tiled layouts (16B chunks):
//  A-tile (64 rows x 64 k, 8 KB, 512 ch): ch = r*8 + (kc ^ (r&7)); chunk
//    (r,c) holds k-block c^(r&7) of row r.  adjT: [b][mt(32)][kk(32)][512ch].
//  B-tile (128 n x 64 k, 16 KB, 1024 ch): same formula with n as row.
//    xTt/hT: [b][kk(32)][1024 ch]  (kk = source-node block of 64).
//  WTg per layer (32 KB, 2048 ch): ch = n*16 + half*8 + (kc8 ^ (n&7)),
//    half = k>>6, kc8 = (k&63)>>3  (k-contig bf16x8 frags of W^T[n][k]).
// ---------------------------------------------------------------------------

// prep: W (128x128 fp32, [k][n]) -> swizzled WT tiles, for all 3 layers
__global__ __launch_bounds__(256) void prep_wt(const float* __restrict__ W0,
                                               const float* __restrict__ W1,
                                               const float* __restrict__ W2,
                                               bf16* __restrict__ WTg) {
    int l = blockIdx.x;
    const float* W = (l == 0) ? W0 : (l == 1) ? W1 : W2;
    bf16* out = WTg + l * 16384;
    int tid = threadIdx.x;
#pragma unroll
    for (int i = 0; i < 8; ++i) {
        int p = i * 256 + tid;                 // [0,2048)
        int n = p >> 4, half = (p >> 3) & 1, cs = p & 7;
        int kc = cs ^ (n & 7);
        int kbase = half * 64 + kc * 8;
        bf16x8 o;
#pragma unroll
        for (int r = 0; r < 8; ++r) o[r] = (bf16)W[(kbase + r) * 128 + n];
        *(bf16x8*)(out + p * 8) = o;
    }
}

// prep: x (16,2048,128) fp32 -> xTt tiled bf16 B-tiles
__global__ __launch_bounds__(256) void prep_xt(const float* __restrict__ x,
                                               bf16* __restrict__ xTt) {
    __shared__ bf16 T[128 * 136];
    const int blk = blockIdx.x;            // 256 blocks: 16 node-tiles x 16 b
    const int b = blk >> 4, node0 = (blk & 15) * 128;
    const int tid = threadIdx.x;
    const float* xb = x + ((size_t)b * NN + node0) * HID;
#pragma unroll
    for (int i = 0; i < 64; ++i) {
        int idx = i * 256 + tid;
        int node = idx >> 7, hid = idx & 127;
        T[hid * 136 + node] = (bf16)xb[(size_t)node * HID + hid];
    }
    __syncthreads();
#pragma unroll
    for (int i = 0; i < 8; ++i) {
        int p = i * 256 + tid;                 // [0,2048) chunks (2 tiles)
        int half = p >> 10, p1 = p & 1023;
        int n = p1 >> 3, cs = p1 & 7, c = cs ^ (n & 7), m = half * 64 + c * 8;
        *(bf16x8*)(xTt + ((size_t)b * 32 + (node0 >> 6) + half) * 8192 + p1 * 8)
            = *(const bf16x8*)(T + n * 136 + m);
    }
}

// ---------------------------------------------------------------------------
// layer: g = adj[b](64-row slab) @ h[b]; then h' = relu(LN(g@W + bias)).
// BM=64, BN=128, BK=64, 32 K-steps, 4 waves, grid 512 -> 2 blocks/CU.
// TRIPLE-buffered LDS (3 x 24 KB = 72 KB): slack 2 K-steps, ONE barrier +
// counted vmcnt(6) per step.  WT fragments read from global in epilogue.
// AMODE 1: A from fp32 adj (coalesced 128B segs -> regs -> cvt -> ds_write
//          + tiled adjT side-write).  AMODE 2: A via linear gload_lds.
// ---------------------------------------------------------------------------
template<int AMODE, bool FINAL>
__global__ __launch_bounds__(256, 2) void layer64(
        const float* __restrict__ Af, bf16* __restrict__ adjT,
        const bf16* __restrict__ Bt, const bf16* __restrict__ WTg,
        const float* __restrict__ bias, const float* __restrict__ gam,
        const float* __restrict__ bet, bf16* __restrict__ hOut,
        float* __restrict__ outF) {
    __shared__ __align__(16) bf16 lds[36864];   // 3 x 12288 elems (A 4096 + B 8192)

    const int tid = threadIdx.x, wave = tid >> 6, lane = tid & 63;
    const int c0 = lane & 15, q = lane >> 4;
    const int blk = blockIdx.x, xcd = blk & 7, jj = blk >> 3;
    const int b = xcd * 2 + (jj & 1);          // each XCD owns 2 batches
    const int mt = jj >> 1, m0 = mt * 64;      // [0,32) m-tiles of 64 rows

    const bf16* Btb = Bt + (size_t)b * 32 * 8192;
    bf16* Atl = adjT + ((size_t)b * 32 + mt) * (size_t)(32 * 4096);
    const float* Afb = Af + (size_t)b * NN * NN + (size_t)m0 * NN;

    f32x4 acc[8] = {};

    auto stageA = [&](int buf, int kk) {       // 512 ch, 2 gload/wave, linear
#pragma unroll
        for (int j = 0; j < 2; ++j) {
            int cb = j * 256 + wave * 64;
            gload_lds16(Atl + (size_t)kk * 4096 + (size_t)(cb + lane) * 8,
                        lds + buf * 12288 + cb * 8);
        }
    };
    auto stageB = [&](int buf, int kk) {       // 1024 ch, 4 gload/wave, linear
#pragma unroll
        for (int j = 0; j < 4; ++j) {
            int cb = j * 256 + wave * 64;
            gload_lds16(Btb + (size_t)kk * 8192 + (size_t)(cb + lane) * 8,
                        lds + buf * 12288 + 4096 + cb * 8);
        }
    };

    int g_row[2], g_cb[2];
#pragma unroll
    for (int j = 0; j < 2; ++j) {
        int gi = j * 256 + tid;
        g_row[j] = gi >> 3; g_cb[j] = gi & 7;   // 8 thr/row: 128B segments
    }
    f32x4 va[2], vb[2];
    auto loadA = [&](int kk) {
#pragma unroll
        for (int j = 0; j < 2; ++j) {
            const float* s = Afb + (size_t)g_row[j] * NN + kk * 64 + g_cb[j] * 8;
            va[j] = *(const f32x4*)s;
            vb[j] = *(const f32x4*)(s + 4);
        }
    };
    auto writeA = [&](int buf, int kk) {
#pragma unroll
        for (int j = 0; j < 2; ++j) {
            bf16x8 o = {(bf16)va[j].x, (bf16)va[j].y, (bf16)va[j].z, (bf16)va[j].w,
                        (bf16)vb[j].x, (bf16)vb[j].y, (bf16)vb[j].z, (bf16)vb[j].w};
            int ch = g_row[j] * 8 + (g_cb[j] ^ (g_row[j] & 7));
            *(bf16x8*)(lds + buf * 12288 + ch * 8) = o;
            *(bf16x8*)(Atl + (size_t)kk * 4096 + ch * 8) = o;   // tiled side-write
        }
    };
    auto compute = [&](int buf) {
        const bf16* As = lds + buf * 12288;
        const bf16* Bs = As + 4096;
#pragma unroll
        for (int ks = 0; ks < 2; ++ks) {
            int kb = ks * 4 + q;
            int ar = wave * 16 + c0;
            bf16x8 af = *(const bf16x8*)(As + ar * 64 + (kb ^ (ar & 7)) * 8);
#pragma unroll
            for (int nt = 0; nt < 8; ++nt) {
                int br = nt * 16 + c0;
                bf16x8 bw = *(const bf16x8*)(Bs + br * 64 + (kb ^ (br & 7)) * 8);
                acc[nt] = __builtin_amdgcn_mfma_f32_16x16x32_bf16(af, bw, acc[nt], 0, 0, 0);
            }
        }
    };

    // ---- prologue: tiles 0,1 staged (bufs 0,1) ----
    if constexpr (AMODE == 1) {
        loadA(0); writeA(0, 0); stageB(0, 0);
        loadA(1); writeA(1, 1); stageB(1, 1);
    } else {
        stageA(0, 0); stageB(0, 0);
        stageA(1, 1); stageB(1, 1);
    }

    // ---- main loop: 1 barrier + counted vmcnt per step; stage kk+2 ----
    int bufk = 0;                               // = kk % 3
#pragma unroll 1
    for (int kk = 0; kk < 32; ++kk) {
        if (kk < 31) WAITV(6);                  // tile kk landed (mine); barrier
        else         WAITV(0);                  //   makes it true for all waves
        __builtin_amdgcn_s_barrier();
        const int b2 = bufk ? bufk - 1 : 2;     // (kk+2) % 3
        if constexpr (AMODE == 1) {
            if (kk < 30) loadA(kk + 2);         // issue early: hide under MFMA
            compute(bufk);
            if (kk < 30) { writeA(b2, kk + 2); stageB(b2, kk + 2); }
        } else {
            compute(bufk);
            if (kk < 30) { stageA(b2, kk + 2); stageB(b2, kk + 2); }
        }
        bufk = (bufk == 2) ? 0 : bufk + 1;
    }
    __syncthreads();                            // LDS buffers dead

    // ---- epilogue: g-tile bf16 -> G = lds[0..8704) as [64][136] ----
    bf16* G = lds;
#pragma unroll
    for (int nt = 0; nt < 8; ++nt)
#pragma unroll
        for (int r = 0; r < 4; ++r) {
            int row = wave * 16 + q * 4 + r;
            G[row * 136 + nt * 16 + c0] = (bf16)acc[nt][r];
        }
    __syncthreads();

    // ---- W-GEMM: h(64x128) = G @ W ; W-frags straight from global (L1/L2) --
    f32x4 a2[8] = {};
    {
        const int gr = wave * 16 + c0;
#pragma unroll
        for (int ks = 0; ks < 4; ++ks) {
            bf16x8 af = *(const bf16x8*)(G + gr * 136 + ks * 32 + q * 8);
#pragma unroll
            for (int nt = 0; nt < 8; ++nt) {
                int n = nt * 16 + c0;
                int ch = n * 16 + (ks >> 1) * 8 + ((((ks & 1) << 2) | q) ^ (n & 7));
                bf16x8 bw = *(const bf16x8*)(WTg + (size_t)ch * 8);
                a2[nt] = __builtin_amdgcn_mfma_f32_16x16x32_bf16(af, bw, a2[nt], 0, 0, 0);
            }
        }
    }

    // ---- bias + LN(over n=128) + ReLU ----
    float bv[8], gv[8], ev[8];
#pragma unroll
    for (int nt = 0; nt < 8; ++nt) {
        int n = nt * 16 + c0;
        bv[nt] = bias[n]; gv[nt] = gam[n]; ev[nt] = bet[n];
    }
    bf16* Cs = lds;   // [128 n][72] node-minor; aliases G (post-barrier)
    if constexpr (!FINAL) __syncthreads();      // all W-GEMM reads of G done
#pragma unroll
    for (int r = 0; r < 4; ++r) {
        float v[8], s1 = 0.f, s2 = 0.f;
#pragma unroll
        for (int nt = 0; nt < 8; ++nt) {
            float xv = a2[nt][r] + bv[nt];
            v[nt] = xv; s1 += xv; s2 += xv * xv;
        }
#pragma unroll
        for (int off = 1; off < 16; off <<= 1) {
            s1 += __shfl_xor(s1, off);
            s2 += __shfl_xor(s2, off);
        }
        float mu = s1 * (1.f / 128.f);
        float var = s2 * (1.f / 128.f) - mu * mu;
        float rs = rsqrtf(var + 1e-5f);
        int row = wave * 16 + q * 4 + r;        // local node row in [0,64)
        if constexpr (FINAL) {
            size_t ro = ((size_t)b * NN + m0 + row) * HID;
#pragma unroll
            for (int nt = 0; nt < 8; ++nt) {
                float o = fmaxf((v[nt] - mu) * rs * gv[nt] + ev[nt], 0.f);
                outF[ro + nt * 16 + c0] = o;
            }
        } else {
#pragma unroll
            for (int nt = 0; nt < 8; ++nt) {
                float o = fmaxf((v[nt] - mu) * rs * gv[nt] + ev[nt], 0.f);
                Cs[(nt * 16 + c0) * 72 + row] = (bf16)o;
            }
        }
    }
    if constexpr (!FINAL) {
        __syncthreads();
        // write this block's B-tile (kk = mt), fully linear
#pragma unroll
        for (int i = 0; i < 4; ++i) {
            int p1 = i * 256 + tid;             // [0,1024)
            int n = p1 >> 3, cs = p1 & 7, c = cs ^ (n & 7), m = c * 8;
            *(bf16x8*)(hOut + ((size_t)b * 32 + mt) * 8192 + p1 * 8)
                = *(const bf16x8*)(Cs + n * 72 + m);
        }
    }
}

// ---------------------------------------------------------------------------
extern "C" void kernel_launch(void* const* d_in, const int* in_sizes, int n_in,
                              void* d_out, int out_size, void* d_ws, size_t ws_size,
                              hipStream_t stream) {
    const float* x   = (const float*)d_in[0];
    const float* adj = (const float*)d_in[1];
    const float* W[3]  = {(const float*)d_in[2],  (const float*)d_in[6],  (const float*)d_in[10]};
    const float* bb[3] = {(const float*)d_in[3],  (const float*)d_in[7],  (const float*)d_in[11]};
    const float* gg[3] = {(const float*)d_in[4],  (const float*)d_in[8],  (const float*)d_in[12]};
    const float* be[3] = {(const float*)d_in[5],  (const float*)d_in[9],  (const float*)d_in[13]};

    char* ws = (char*)d_ws;
    size_t off = 0;
    auto alloc = [&](size_t bytes) {
        char* p = ws + off; off = (off + bytes + 255) & ~(size_t)255; return p;
    };
    bf16* WTg  = (bf16*)alloc((size_t)3 * 16384 * 2);
    bf16* xTt  = (bf16*)alloc((size_t)NB * 32 * 8192 * 2);            // 8 MiB
    bf16* hT0  = (bf16*)alloc((size_t)NB * 32 * 8192 * 2);            // 8 MiB
    bf16* hT1  = (bf16*)alloc((size_t)NB * 32 * 8192 * 2);            // 8 MiB
    bf16* adjT = (bf16*)alloc((size_t)NB * 32 * 32 * 4096 * 2);       // 128 MiB

    float* outF = (float*)d_out;

    prep_wt<<<3, 256, 0, stream>>>(W[0], W[1], W[2], WTg);
    prep_xt<<<256, 256, 0, stream>>>(x, xTt);

    layer64<1, false><<<512, 256, 0, stream>>>(adj, adjT, xTt, WTg,
                                               bb[0], gg[0], be[0], hT0, nullptr);
    layer64<2, false><<<512, 256, 0, stream>>>(adj, adjT, hT0, WTg + 16384,
                                               bb[1], gg[1], be[1], hT1, nullptr);
    layer64<2, true ><<<512, 256, 0, stream>>>(adj, adjT, hT1, WTg + 2 * 16384,
                                               bb[2], gg[2], be[2], nullptr, outF);
}

// Round 7
// 503.612 us; speedup vs baseline: 1.1056x; 1.0204x over previous
//
#include <hip/hip_runtime.h>
#include <hip/hip_bf16.h>

typedef __bf16 bf16;
typedef __bf16 bf16x8 __attribute__((ext_vector_type(8)));
typedef float  f32x4  __attribute__((ext_vector_type(4)));

static constexpr int NB  = 16;
static constexpr int NN  = 2048;
static constexpr int HID = 128;

// async 16B global -> LDS. LDS dest is wave-uniform base (+ lane*16 in HW);
// global src address IS per-lane (must carry the lane term!).
__device__ __forceinline__ void gload_lds16(const bf16* g, bf16* l) {
    __builtin_amdgcn_global_load_lds(
        (const __attribute__((address_space(1))) unsigned int*)g,
        (__attribute__((address_space(3))) unsigned int*)l, 16, 0, 0);
}

#define WAITV(n) asm volatile("s_waitcnt vmcnt(" #n ")" ::: "memory")

// ---------------------------------------------------------------------------
// Tiled layouts ("LDS images", 16 KB tiles of 1024 16B-chunks):
//   A-tile (128 rows x 64 k): chunk p = row*8 + (kc ^ (row&7)), kc = k/8
//   B-tile (128 n   x 64 k): same formula with n as row
//   adjT[b][mtile(16)][kk(32)] tiles ; xTt/hT: [b][kk(32)] tiles
//   WTg per layer: 2048 chunks: chunk = n*16 + half*8 + (kc8 ^ (n&7)),
//     half = k>>6, kc8 = (k&63)>>3  (k-contig bf16x8 fragments of W^T[n][k])
// ---------------------------------------------------------------------------

// prep: W (128x128 fp32, [k][n]) -> swizzled WT tiles, for all 3 layers
__global__ __launch_bounds__(256) void prep_wt(const float* __restrict__ W0,
                                               const float* __restrict__ W1,
                                               const float* __restrict__ W2,
                                               bf16* __restrict__ WTg) {
    int l = blockIdx.x;
    const float* W = (l == 0) ? W0 : (l == 1) ? W1 : W2;
    bf16* out = WTg + l * 16384;
    int tid = threadIdx.x;
#pragma unroll
    for (int i = 0; i < 8; ++i) {
        int p = i * 256 + tid;                 // [0,2048)
        int n = p >> 4, half = (p >> 3) & 1, cs = p & 7;
        int kc = cs ^ (n & 7);
        int kbase = half * 64 + kc * 8;
        bf16x8 o;
#pragma unroll
        for (int r = 0; r < 8; ++r) o[r] = (bf16)W[(kbase + r) * 128 + n];
        *(bf16x8*)(out + p * 8) = o;
    }
}

// prep: x (16,2048,128) fp32 -> xTt tiled bf16 B-tiles
__global__ __launch_bounds__(256) void prep_xt(const float* __restrict__ x,
                                               bf16* __restrict__ xTt) {
    __shared__ bf16 T[128 * 136];
    const int blk = blockIdx.x;            // 256 blocks: 16 node-tiles x 16 b
    const int b = blk >> 4, node0 = (blk & 15) * 128;
    const int tid = threadIdx.x;
    const float* xb = x + ((size_t)b * NN + node0) * HID;
#pragma unroll
    for (int i = 0; i < 64; ++i) {
        int idx = i * 256 + tid;
        int node = idx >> 7, hid = idx & 127;
        T[hid * 136 + node] = (bf16)xb[(size_t)node * HID + hid];
    }
    __syncthreads();
#pragma unroll
    for (int i = 0; i < 8; ++i) {
        int p = i * 256 + tid;                 // [0,2048) chunks (2 tiles)
        int half = p >> 10, p1 = p & 1023;
        int n = p1 >> 3, cs = p1 & 7, c = cs ^ (n & 7), m = half * 64 + c * 8;
        *(bf16x8*)(xTt + ((size_t)b * 32 + (node0 >> 6) + half) * 8192 + p1 * 8)
            = *(const bf16x8*)(T + n * 136 + m);
    }
}

// ---------------------------------------------------------------------------
// fused layer: g = adj[b] @ h[b]  (BM=128, BN=128, BK=64, 32 K-steps, 8 waves)
//   then epilogue: h' = relu(LN(g @ W + bias)), written as tiled B for next.
// R3 champion structure + (a) QUAD-buffered AMODE2 pipeline (stage 3 ahead,
// counted vmcnt(8), one barrier/step), (b) WT read from global in epilogue,
// (c) s_setprio around the MFMA cluster.
// AMODE 1: A from fp32 adj (coalesced 256B segs) + tiled side-write adjT,
//          2-deep __syncthreads pipeline (near HBM floor already).
// AMODE 2: A from adjT via linear global_load_lds.
// ---------------------------------------------------------------------------
template<int AMODE, bool FINAL>
__global__ __launch_bounds__(512, 2) void fused_layer(
        const float* __restrict__ Af, bf16* __restrict__ adjT,
        const bf16* __restrict__ Bt, const bf16* __restrict__ WTg,
        const float* __restrict__ bias, const float* __restrict__ gam,
        const float* __restrict__ bet, bf16* __restrict__ hOut,
        float* __restrict__ outF) {
    // 4 step-buffers x 16384 elems (A 8192 + B 8192) = 128 KB
    __shared__ __align__(16) bf16 lds[65536];

    const int tid = threadIdx.x, wave = tid >> 6, lane = tid & 63;
    const int c0 = lane & 15, q = lane >> 4;
    const int blk = blockIdx.x, xcd = blk & 7, jj = blk >> 3;
    const int b = xcd * 2 + (jj & 1);       // each XCD owns 2 batches
    const int mtile = jj >> 1, m0 = mtile * 128;
    const int wm = wave >> 1, wn = wave & 1;

    const bf16* Btb = Bt + (size_t)b * 32 * 8192;
    bf16* Atl = adjT + ((size_t)b * 16 + mtile) * (size_t)32 * 8192;

    f32x4 acc[2][4] = {};

    auto stageA2 = [&](int buf, int kk) {    // 2 loads/wave, linear 16KB
#pragma unroll
        for (int j = 0; j < 2; ++j) {
            int cb = j * 512 + wave * 64;
            gload_lds16(Atl + (size_t)kk * 8192 + (size_t)(cb + lane) * 8,
                        lds + buf * 16384 + cb * 8);
        }
    };
    auto stageB2 = [&](int buf, int kk) {    // 2 loads/wave, linear 16KB
#pragma unroll
        for (int j = 0; j < 2; ++j) {
            int cb = j * 512 + wave * 64;
            gload_lds16(Btb + (size_t)kk * 8192 + (size_t)(cb + lane) * 8,
                        lds + buf * 16384 + 8192 + cb * 8);
        }
    };
    auto compute = [&](int buf) {
        const bf16* As = lds + buf * 16384;
        const bf16* Bs = As + 8192;
#pragma unroll
        for (int ks = 0; ks < 2; ++ks) {
            bf16x8 af[2], bf_[4];
#pragma unroll
            for (int mt = 0; mt < 2; ++mt) {
                int row = wm * 32 + mt * 16 + c0;
                int cb = (ks * 4 + q) ^ (row & 7);
                af[mt] = *(const bf16x8*)(As + row * 64 + cb * 8);
            }
#pragma unroll
            for (int nt = 0; nt < 4; ++nt) {
                int row = wn * 64 + nt * 16 + c0;
                int cb = (ks * 4 + q) ^ (row & 7);
                bf_[nt] = *(const bf16x8*)(Bs + row * 64 + cb * 8);
            }
            __builtin_amdgcn_s_setprio(1);
#pragma unroll
            for (int mt = 0; mt < 2; ++mt)
#pragma unroll
                for (int nt = 0; nt < 4; ++nt)
                    acc[mt][nt] = __builtin_amdgcn_mfma_f32_16x16x32_bf16(
                        af[mt], bf_[nt], acc[mt][nt], 0, 0, 0);
            __builtin_amdgcn_s_setprio(0);
        }
    };

    if constexpr (AMODE == 1) {
        int grow[2], gcb[2];
#pragma unroll
        for (int j = 0; j < 2; ++j) {
            int gi = j * 512 + tid;
            grow[j] = gi >> 3; gcb[j] = gi & 7;
        }
        f32x4 va[2], vb[2];
        auto loadA = [&](int kk) {
#pragma unroll
            for (int j = 0; j < 2; ++j) {
                const float* s = Af + (size_t)b * NN * NN
                               + (size_t)(m0 + grow[j]) * NN + kk * 64 + gcb[j] * 8;
                va[j] = *(const f32x4*)s;
                vb[j] = *(const f32x4*)(s + 4);
            }
        };
        auto writeA = [&](int buf, int kk) {
#pragma unroll
            for (int j = 0; j < 2; ++j) {
                bf16x8 o = {(bf16)va[j].x, (bf16)va[j].y, (bf16)va[j].z, (bf16)va[j].w,
                            (bf16)vb[j].x, (bf16)vb[j].y, (bf16)vb[j].z, (bf16)vb[j].w};
                int ch = grow[j] * 8 + (gcb[j] ^ (grow[j] & 7));
                *(bf16x8*)(lds + buf * 16384 + ch * 8) = o;
                *(bf16x8*)(Atl + (size_t)kk * 8192 + ch * 8) = o;  // tiled side-write
            }
        };
        loadA(0); stageB2(0, 0); writeA(0, 0);
        __syncthreads();
        int cur = 0;
        for (int kk = 0; kk < 32; ++kk) {
            if (kk < 31) { loadA(kk + 1); stageB2(cur ^ 1, kk + 1); }
            compute(cur);
            if (kk < 31) writeA(cur ^ 1, kk + 1);
            __syncthreads();
            cur ^= 1;
        }
    } else {
        // prologue: tiles 0,1,2 in flight (4 gloads/wave each -> 12)
        stageA2(0, 0); stageB2(0, 0);
        stageA2(1, 1); stageB2(1, 1);
        stageA2(2, 2); stageB2(2, 2);
#pragma unroll 1
        for (int kk = 0; kk < 32; ++kk) {
            // in-order retirement: wait until tile kk's 4 loads (mine) landed;
            // barrier makes it true for ALL waves' portions.
            if (kk <= 29)      WAITV(8);
            else if (kk == 30) WAITV(4);
            else               WAITV(0);
            __builtin_amdgcn_s_barrier();
            asm volatile("" ::: "memory");
            compute(kk & 3);
            asm volatile("" ::: "memory");
            // stage kk+3 into buffer (kk+3)&3 == (kk-1)&3: its last reader
            // (compute kk-1) finished before this iteration's barrier.
            if (kk <= 28) { stageA2((kk + 3) & 3, kk + 3); stageB2((kk + 3) & 3, kk + 3); }
        }
        __syncthreads();
    }

    // ---- epilogue: store g-tile bf16 to LDS [128][136] (dbuf area dead) ----
    bf16* G = lds;
#pragma unroll
    for (int mt = 0; mt < 2; ++mt)
#pragma unroll
        for (int r = 0; r < 4; ++r) {
            int row = wm * 32 + mt * 16 + q * 4 + r;
#pragma unroll
            for (int nt = 0; nt < 4; ++nt) {
                int col = wn * 64 + nt * 16 + c0;
                G[row * 136 + col] = (bf16)acc[mt][nt][r];
            }
        }
    __syncthreads();

    // ---- W-GEMM: h(128x128) = G @ W ; W-frags from global (L2-resident) ----
    f32x4 a2[8] = {};
    {
        const int gr = wave * 16 + c0;
#pragma unroll
        for (int ks = 0; ks < 4; ++ks) {
            bf16x8 af = *(const bf16x8*)(G + gr * 136 + ks * 32 + q * 8);
#pragma unroll
            for (int nt = 0; nt < 8; ++nt) {
                int n = nt * 16 + c0;
                int ch = n * 16 + (ks >> 1) * 8 + ((((ks & 1) << 2) | q) ^ (n & 7));
                bf16x8 bw = *(const bf16x8*)(WTg + (size_t)ch * 8);
                a2[nt] = __builtin_amdgcn_mfma_f32_16x16x32_bf16(af, bw, a2[nt], 0, 0, 0);
            }
        }
    }

    // ---- bias + LN(over n=128) + ReLU ----
    float bv[8], gv[8], ev[8];
#pragma unroll
    for (int nt = 0; nt < 8; ++nt) {
        int n = nt * 16 + c0;
        bv[nt] = bias[n]; gv[nt] = gam[n]; ev[nt] = bet[n];
    }
    bf16* Cs = lds;  // reuse G area for transpose staging (post-barrier)
    if constexpr (!FINAL) __syncthreads();   // all W-GEMM reads of G done
#pragma unroll
    for (int r = 0; r < 4; ++r) {
        float v[8], s1 = 0.f, s2 = 0.f;
#pragma unroll
        for (int nt = 0; nt < 8; ++nt) {
            float xv = a2[nt][r] + bv[nt];
            v[nt] = xv; s1 += xv; s2 += xv * xv;
        }
#pragma unroll
        for (int off = 1; off < 16; off <<= 1) {
            s1 += __shfl_xor(s1, off);
            s2 += __shfl_xor(s2, off);
        }
        float mu = s1 * (1.f / 128.f);
        float var = s2 * (1.f / 128.f) - mu * mu;
        float rs = rsqrtf(var + 1e-5f);
        int row = wave * 16 + q * 4 + r;      // local row in [0,128)
        if constexpr (FINAL) {
            size_t ro = ((size_t)b * NN + m0 + row) * HID;
#pragma unroll
            for (int nt = 0; nt < 8; ++nt) {
                float o = fmaxf((v[nt] - mu) * rs * gv[nt] + ev[nt], 0.f);
                outF[ro + nt * 16 + c0] = o;
            }
        } else {
#pragma unroll
            for (int nt = 0; nt < 8; ++nt) {
                float o = fmaxf((v[nt] - mu) * rs * gv[nt] + ev[nt], 0.f);
                Cs[(nt * 16 + c0) * 136 + row] = (bf16)o;
            }
        }
    }
    if constexpr (!FINAL) {
        __syncthreads();
        // write 2 tiled B-tiles (kk = mtile*2, mtile*2+1), fully linear
#pragma unroll
        for (int i = 0; i < 4; ++i) {
            int p = i * 512 + tid;            // [0,2048)
            int half = p >> 10, p1 = p & 1023;
            int n = p1 >> 3, cs = p1 & 7, c = cs ^ (n & 7), m = half * 64 + c * 8;
            *(bf16x8*)(hOut + ((size_t)b * 32 + mtile * 2 + half) * 8192 + p1 * 8)
                = *(const bf16x8*)(Cs + n * 136 + m);
        }
    }
}

// ---------------------------------------------------------------------------
extern "C" void kernel_launch(void* const* d_in, const int* in_sizes, int n_in,
                              void* d_out, int out_size, void* d_ws, size_t ws_size,
                              hipStream_t stream) {
    const float* x   = (const float*)d_in[0];
    const float* adj = (const float*)d_in[1];
    const float* W[3]  = {(const float*)d_in[2],  (const float*)d_in[6],  (const float*)d_in[10]};
    const float* bb[3] = {(const float*)d_in[3],  (const float*)d_in[7],  (const float*)d_in[11]};
    const float* gg[3] = {(const float*)d_in[4],  (const float*)d_in[8],  (const float*)d_in[12]};
    const float* be[3] = {(const float*)d_in[5],  (const float*)d_in[9],  (const float*)d_in[13]};

    char* ws = (char*)d_ws;
    size_t off = 0;
    auto alloc = [&](size_t bytes) {
        char* p = ws + off; off = (off + bytes + 255) & ~(size_t)255; return p;
    };
    bf16* WTg  = (bf16*)alloc((size_t)3 * 16384 * 2);
    bf16* xTt  = (bf16*)alloc((size_t)NB * 32 * 8192 * 2);        // 8 MiB
    bf16* hT0  = (bf16*)alloc((size_t)NB * 32 * 8192 * 2);        // 8 MiB
    bf16* hT1  = (bf16*)alloc((size_t)NB * 32 * 8192 * 2);        // 8 MiB
    bf16* adjT = (bf16*)alloc((size_t)NB * 16 * 32 * 8192 * 2);   // 128 MiB

    float* outF = (float*)d_out;

    prep_wt<<<3, 256, 0, stream>>>(W[0], W[1], W[2], WTg);
    prep_xt<<<256, 256, 0, stream>>>(x, xTt);

    fused_layer<1, false><<<256, 512, 0, stream>>>(adj, adjT, xTt, WTg,
                                                   bb[0], gg[0], be[0], hT0, nullptr);
    fused_layer<2, false><<<256, 512, 0, stream>>>(adj, adjT, hT0, WTg + 16384,
                                                   bb[1], gg[1], be[1], hT1, nullptr);
    fused_layer<2, true ><<<256, 512, 0, stream>>>(adj, adjT, hT1, WTg + 2 * 16384,
                                                   bb[2], gg[2], be[2], nullptr, outF);
}